// Round 1
// baseline (2116.588 us; speedup 1.0000x reference)
//
#include <hip/hip_runtime.h>
#include <hip/hip_bf16.h>

#define BGR 4096      // graphs per side
#define NPG 32
#define EPG 128
#define DIM 256
#define D4  64
#define HS  257       // LDS row stride (pad: bank = (row + col) & 31)

// ---------------------------------------------------------------------------
// Fused per-graph CompGCN (2 layers) + mean readout. One block per (side,graph).
// ---------------------------------------------------------------------------
__global__ __launch_bounds__(256, 2) void graph_emb_kernel(
    const float* __restrict__ subj_embs, const float* __restrict__ obj_embs,
    const int* __restrict__ subj_src, const int* __restrict__ subj_dst,
    const int* __restrict__ obj_src, const int* __restrict__ obj_dst,
    const float* __restrict__ WO1, const float* __restrict__ bO1,
    const float* __restrict__ WI1, const float* __restrict__ bI1,
    const float* __restrict__ WO2, const float* __restrict__ bO2,
    const float* __restrict__ WI2, const float* __restrict__ bI2,
    float* __restrict__ g_out /* [2*BGR, 256] */)
{
  __shared__ float shH[32 * HS];     // node embs -> hi agg -> hi2 agg
  __shared__ float shA[32 * HS];     // ho agg -> h1 -> ho2 agg -> h2
  __shared__ int e_src[EPG], e_dst[EPG];
  __shared__ int cnt_in[32], cnt_out[32], off_in[32], off_out[32];
  __shared__ int list_in[EPG], list_out[EPG];
  __shared__ float inv_in[32], inv_out[32];

  const int t = threadIdx.x;
  const int bid = blockIdx.x;
  const int side = bid >> 12;           // 0: subj, 1: obj
  const int g = bid & (BGR - 1);
  const float* __restrict__ embs = side ? obj_embs : subj_embs;
  const int* __restrict__ srcp = side ? obj_src : subj_src;
  const int* __restrict__ dstp = side ? obj_dst : subj_dst;

  // ---- Phase A: load 32x256 node embeddings + edge list ----
  if (t < EPG) {
    e_src[t] = srcp[(g << 7) + t] & 31;
    e_dst[t] = dstp[(g << 7) + t] & 31;
  }
  if (t >= 128 && t < 160) { int v = t - 128; cnt_in[v] = 0; cnt_out[v] = 0; }
  {
    const float* base = embs + (size_t)(g << 5) * DIM;
    #pragma unroll
    for (int i = 0; i < 8; i++) {
      int f = (i << 8) + t;          // 0..2047 float4 slots
      int v = f >> 6, k4 = f & 63;
      float4 x = *(const float4*)(base + v * DIM + (k4 << 2));
      float* d = &shH[v * HS + (k4 << 2)];
      d[0] = x.x; d[1] = x.y; d[2] = x.z; d[3] = x.w;
    }
  }
  __syncthreads();
  if (t < EPG) { atomicAdd(&cnt_in[e_dst[t]], 1); atomicAdd(&cnt_out[e_src[t]], 1); }
  __syncthreads();
  if (t == 0) {
    int a = 0, b = 0;
    for (int v = 0; v < 32; v++) { off_in[v] = a; a += cnt_in[v]; off_out[v] = b; b += cnt_out[v]; }
  }
  __syncthreads();
  if (t < EPG) {  // deterministic CSR scatter (position = rank among earlier equal keys)
    int d = e_dst[t], s = e_src[t]; int pi = 0, po = 0;
    for (int e = 0; e < t; e++) { pi += (e_dst[e] == d) ? 1 : 0; po += (e_src[e] == s) ? 1 : 0; }
    list_in[off_in[d] + pi] = s;
    list_out[off_out[s] + po] = d;
  }
  if (t >= 128 && t < 160) {
    int v = t - 128;
    inv_in[v]  = 1.0f / fmaxf((float)cnt_in[v], 1.0f);
    inv_out[v] = 1.0f / fmaxf((float)cnt_out[v], 1.0f);
  }
  __syncthreads();

  // ---- Phase B: layer-1 aggregation (register accumulate, 8 threads/node) ----
  {
    const int v = t >> 3, p = t & 7;
    float aco[32], aci[32];
    #pragma unroll
    for (int i = 0; i < 32; i++) { aco[i] = 0.f; aci[i] = 0.f; }
    const int din = cnt_in[v], dout = cnt_out[v];
    const int oin = off_in[v], oout = off_out[v];
    for (int n = 0; n < din; n++) {
      const float* row = &shH[list_in[oin + n] * HS];
      #pragma unroll
      for (int i = 0; i < 32; i++) aco[i] += row[p + (((i + v) & 31) << 3)];
    }
    for (int n = 0; n < dout; n++) {
      const float* row = &shH[list_out[oout + n] * HS];
      #pragma unroll
      for (int i = 0; i < 32; i++) aci[i] += row[p + (((i + v) & 31) << 3)];
    }
    const float fi = inv_in[v], fo = inv_out[v];
    __syncthreads();                 // all reads of shH done
    #pragma unroll
    for (int i = 0; i < 32; i++) {
      int d = p + (((i + v) & 31) << 3);
      shA[v * HS + d] = aco[i] * fi;  // ho
      shH[v * HS + d] = aci[i] * fo;  // hi (overwrites input embs)
    }
    __syncthreads();
  }

  // ---- Phase C: layer-1 matmul  h1 = relu(ho@WO1.T + bO1 + hi@WI1.T + bI1) ----
  {
    const int vm = t & 31, jg = t >> 5;     // j = jg*8 + jj
    const float* wo = WO1 + (size_t)(jg * 8) * DIM;
    const float* wi = WI1 + (size_t)(jg * 8) * DIM;
    const float* pa = &shA[vm * HS];
    const float* pb = &shH[vm * HS];
    float acc[8];
    #pragma unroll
    for (int jj = 0; jj < 8; jj++) acc[jj] = 0.f;
    for (int k = 0; k < DIM; k += 8) {
      float a[8], b[8];
      #pragma unroll
      for (int u = 0; u < 8; u++) { a[u] = pa[k + u]; b[u] = pb[k + u]; }
      #pragma unroll
      for (int jj = 0; jj < 8; jj++) {
        const float4* wo4 = (const float4*)(wo + jj * DIM + k);
        const float4* wi4 = (const float4*)(wi + jj * DIM + k);
        float4 w0 = wo4[0], w1 = wo4[1], x0 = wi4[0], x1 = wi4[1];
        acc[jj] += a[0]*w0.x + a[1]*w0.y + a[2]*w0.z + a[3]*w0.w
                 + a[4]*w1.x + a[5]*w1.y + a[6]*w1.z + a[7]*w1.w
                 + b[0]*x0.x + b[1]*x0.y + b[2]*x0.z + b[3]*x0.w
                 + b[4]*x1.x + b[5]*x1.y + b[6]*x1.z + b[7]*x1.w;
      }
    }
    float h1v[8];
    #pragma unroll
    for (int jj = 0; jj < 8; jj++) {
      int j = jg * 8 + jj;
      h1v[jj] = fmaxf(acc[jj] + bO1[j] + bI1[j], 0.f);
    }
    __syncthreads();                 // matmul reads of shA/shH done
    #pragma unroll
    for (int jj = 0; jj < 8; jj++) shA[vm * HS + jg * 8 + jj] = h1v[jj];
    __syncthreads();
  }

  // ---- Phase D: layer-2 aggregation over h1 (64 dims) ----
  {
    const int v = t >> 3, p = t & 7;
    float aco[8], aci[8];
    #pragma unroll
    for (int i = 0; i < 8; i++) { aco[i] = 0.f; aci[i] = 0.f; }
    const int din = cnt_in[v], dout = cnt_out[v];
    const int oin = off_in[v], oout = off_out[v];
    for (int n = 0; n < din; n++) {
      const float* row = &shA[list_in[oin + n] * HS];
      #pragma unroll
      for (int i = 0; i < 8; i++) aco[i] += row[p + (((i + v) & 7) << 3)];
    }
    for (int n = 0; n < dout; n++) {
      const float* row = &shA[list_out[oout + n] * HS];
      #pragma unroll
      for (int i = 0; i < 8; i++) aci[i] += row[p + (((i + v) & 7) << 3)];
    }
    const float fi = inv_in[v], fo = inv_out[v];
    __syncthreads();                 // all reads of shA (h1) done
    #pragma unroll
    for (int i = 0; i < 8; i++) {
      int d = p + (((i + v) & 7) << 3);
      shA[v * HS + d] = aco[i] * fi;  // ho2
      shH[v * HS + d] = aci[i] * fo;  // hi2
    }
    __syncthreads();
  }

  // ---- Phase E: layer-2 matmul  h2 = relu(ho2@WO2.T + bO2 + hi2@WI2.T + bI2) ----
  {
    const int vm = t & 31, jg = t >> 5;      // j = jg*32 + jj
    const float* wo = WO2 + (size_t)(jg * 32) * D4;
    const float* wi = WI2 + (size_t)(jg * 32) * D4;
    const float* pa = &shA[vm * HS];
    const float* pb = &shH[vm * HS];
    float acc[32];
    #pragma unroll
    for (int jj = 0; jj < 32; jj++) acc[jj] = 0.f;
    for (int k0 = 0; k0 < D4; k0 += 16) {
      float a[16], b[16];
      #pragma unroll
      for (int u = 0; u < 16; u++) { a[u] = pa[k0 + u]; b[u] = pb[k0 + u]; }
      #pragma unroll
      for (int jj = 0; jj < 32; jj++) {
        const float* wr = wo + jj * D4 + k0;
        const float* xr = wi + jj * D4 + k0;
        #pragma unroll
        for (int u = 0; u < 16; u += 4) {
          float4 w = *(const float4*)(wr + u);
          float4 x = *(const float4*)(xr + u);
          acc[jj] += a[u]*w.x + a[u+1]*w.y + a[u+2]*w.z + a[u+3]*w.w
                   + b[u]*x.x + b[u+1]*x.y + b[u+2]*x.z + b[u+3]*x.w;
        }
      }
    }
    #pragma unroll
    for (int jj = 0; jj < 32; jj++) {
      int j = jg * 32 + jj;
      acc[jj] = fmaxf(acc[jj] + bO2[j] + bI2[j], 0.f);
    }
    __syncthreads();                 // matmul reads done
    #pragma unroll
    for (int jj = 0; jj < 32; jj++) shA[vm * HS + jg * 32 + jj] = acc[jj];
    __syncthreads();
  }

  // ---- Phase F: mean readout over 32 nodes ----
  {
    float s = 0.f;
    #pragma unroll
    for (int v = 0; v < 32; v++) s += shA[v * HS + t];
    g_out[((size_t)(side * BGR + g)) * DIM + t] = s * (1.0f / 32.0f);
  }
}

// ---------------------------------------------------------------------------
// r_embs = relu(rel @ relW.T + relb). 16 rows per block.
// ---------------------------------------------------------------------------
__global__ __launch_bounds__(256, 4) void rel_kernel(
    const float* __restrict__ rel, const float* __restrict__ relW,
    const float* __restrict__ relb, float* __restrict__ r_out)
{
  __shared__ float srel[16 * HS];
  const int t = threadIdx.x;
  const int b0 = blockIdx.x << 4;
  #pragma unroll
  for (int i = 0; i < 4; i++) {
    int f = (i << 8) + t;            // 0..1023 float4 slots
    int r = f >> 6, k4 = f & 63;
    float4 x = *(const float4*)(rel + (size_t)(b0 + r) * DIM + (k4 << 2));
    float* d = &srel[r * HS + (k4 << 2)];
    d[0] = x.x; d[1] = x.y; d[2] = x.z; d[3] = x.w;
  }
  __syncthreads();
  const int r = t & 15, jg = t >> 4;          // j = jg*16 + jj
  const float* pa = &srel[r * HS];
  const float* w = relW + (size_t)(jg * 16) * DIM;
  float acc[16];
  #pragma unroll
  for (int jj = 0; jj < 16; jj++) acc[jj] = 0.f;
  for (int k0 = 0; k0 < DIM; k0 += 16) {
    float a[16];
    #pragma unroll
    for (int u = 0; u < 16; u++) a[u] = pa[k0 + u];
    #pragma unroll
    for (int jj = 0; jj < 16; jj++) {
      const float* wr = w + jj * DIM + k0;
      #pragma unroll
      for (int u = 0; u < 16; u += 4) {
        float4 wv = *(const float4*)(wr + u);
        acc[jj] += a[u]*wv.x + a[u+1]*wv.y + a[u+2]*wv.z + a[u+3]*wv.w;
      }
    }
  }
  float* outp = r_out + (size_t)(b0 + r) * DIM + jg * 16;
  #pragma unroll
  for (int jj = 0; jj < 16; jj++) outp[jj] = fmaxf(acc[jj] + relb[jg * 16 + jj], 0.f);
}

// ---------------------------------------------------------------------------
// Distances: pos = ||h+r-t||, neg = ||h[ch]+r-t[ct]||. One wave per triple.
// ---------------------------------------------------------------------------
__global__ __launch_bounds__(256) void dist_kernel(
    const float* __restrict__ hemb, const float* __restrict__ temb,
    const float* __restrict__ remb, const int* __restrict__ chx,
    const int* __restrict__ ctx, float* __restrict__ out)
{
  const int t = threadIdx.x;
  const int w = t >> 6, l = t & 63;
  const int b = (blockIdx.x << 2) + w;
  float4 h4 = *(const float4*)(hemb + (size_t)b * DIM + (l << 2));
  float4 r4 = *(const float4*)(remb + (size_t)b * DIM + (l << 2));
  float4 t4 = *(const float4*)(temb + (size_t)b * DIM + (l << 2));
  int hb = chx[b], tb = ctx[b];
  float4 hn = *(const float4*)(hemb + (size_t)hb * DIM + (l << 2));
  float4 tn = *(const float4*)(temb + (size_t)tb * DIM + (l << 2));
  float x0 = h4.x + r4.x - t4.x, x1 = h4.y + r4.y - t4.y;
  float x2 = h4.z + r4.z - t4.z, x3 = h4.w + r4.w - t4.w;
  float dp = x0*x0 + x1*x1 + x2*x2 + x3*x3;
  float y0 = hn.x + r4.x - tn.x, y1 = hn.y + r4.y - tn.y;
  float y2 = hn.z + r4.z - tn.z, y3 = hn.w + r4.w - tn.w;
  float dn = y0*y0 + y1*y1 + y2*y2 + y3*y3;
  #pragma unroll
  for (int off = 32; off >= 1; off >>= 1) {
    dp += __shfl_down(dp, off);
    dn += __shfl_down(dn, off);
  }
  if (l == 0) {
    out[b] = sqrtf(dp);
    out[BGR + b] = sqrtf(dn);
  }
}

extern "C" void kernel_launch(void* const* d_in, const int* in_sizes, int n_in,
                              void* d_out, int out_size, void* d_ws, size_t ws_size,
                              hipStream_t stream) {
  const float* subj_embs = (const float*)d_in[0];
  const float* obj_embs  = (const float*)d_in[1];
  const float* rel_tok   = (const float*)d_in[2];
  const int* subj_src = (const int*)d_in[3];
  const int* subj_dst = (const int*)d_in[4];
  const int* obj_src  = (const int*)d_in[5];
  const int* obj_dst  = (const int*)d_in[6];
  // d_in[7] = node_graph_ids (implicit by construction)
  const int* chx = (const int*)d_in[8];
  const int* ctx = (const int*)d_in[9];
  const float* WO1 = (const float*)d_in[10];
  const float* bO1 = (const float*)d_in[11];
  const float* WI1 = (const float*)d_in[12];
  const float* bI1 = (const float*)d_in[13];
  const float* WO2 = (const float*)d_in[14];
  const float* bO2 = (const float*)d_in[15];
  const float* WI2 = (const float*)d_in[16];
  const float* bI2 = (const float*)d_in[17];
  const float* relW = (const float*)d_in[18];
  const float* relb = (const float*)d_in[19];

  float* g_embs = (float*)d_ws;                    // [2*BGR, 256] subj then obj
  float* r_embs = g_embs + (size_t)2 * BGR * DIM;  // [BGR, 256]
  float* out = (float*)d_out;                      // [2*BGR]: pos then neg

  graph_emb_kernel<<<2 * BGR, 256, 0, stream>>>(
      subj_embs, obj_embs, subj_src, subj_dst, obj_src, obj_dst,
      WO1, bO1, WI1, bI1, WO2, bO2, WI2, bI2, g_embs);
  rel_kernel<<<BGR / 16, 256, 0, stream>>>(rel_tok, relW, relb, r_embs);
  dist_kernel<<<BGR / 4, 256, 0, stream>>>(
      g_embs, g_embs + (size_t)BGR * DIM, r_embs, chx, ctx, out);
}

// Round 2
// 251.187 us; speedup vs baseline: 8.4263x; 8.4263x over previous
//
#include <hip/hip_runtime.h>
#include <hip/hip_bf16.h>

#define BGR 4096      // graphs per side
#define DIM 256
#define HS  257       // LDS row stride for rel_kernel (fp32)

typedef __bf16 bf16x8 __attribute__((ext_vector_type(8)));
typedef float  f32x4  __attribute__((ext_vector_type(4)));
typedef unsigned short u16x4 __attribute__((ext_vector_type(4)));

__device__ __forceinline__ unsigned short f2b(float f) {
  unsigned u = __builtin_bit_cast(unsigned, f);
  u = (u + 0x7FFFu + ((u >> 16) & 1u)) >> 16;   // RNE
  return (unsigned short)u;
}

// ---------------------------------------------------------------------------
// Weight prep: W1cat=[WO1|WI1] bf16 [64][512], W2cat=[WO2|WI2] bf16 [256][128],
// b1 = bO1+bI1 (f32[64]), b2 = bO2+bI2 (f32[256]).
// ---------------------------------------------------------------------------
__global__ void wcvt_kernel(
    const float* __restrict__ WO1, const float* __restrict__ WI1,
    const float* __restrict__ WO2, const float* __restrict__ WI2,
    const float* __restrict__ bO1, const float* __restrict__ bI1,
    const float* __restrict__ bO2, const float* __restrict__ bI2,
    unsigned short* __restrict__ W1b, unsigned short* __restrict__ W2b,
    float* __restrict__ b1, float* __restrict__ b2)
{
  const int i = blockIdx.x * 256 + threadIdx.x;   // 0..32767
  { int j = i >> 9, k = i & 511;
    float v = (k < 256) ? WO1[j * 256 + k] : WI1[j * 256 + (k - 256)];
    W1b[i] = f2b(v); }
  { int j = i >> 7, k = i & 127;
    float v = (k < 64) ? WO2[j * 64 + k] : WI2[j * 64 + (k - 64)];
    W2b[i] = f2b(v); }
  if (i < 64)  b1[i] = bO1[i] + bI1[i];
  if (i < 256) b2[i] = bO2[i] + bI2[i];
}

// ---------------------------------------------------------------------------
// Fused per-graph CompGCN (2 layers, all MFMA bf16) + mean readout.
// One block per (side, graph). 256 threads = 4 waves.
//
// LDS map (bytes):
//   [0,     20480) EbT   256 rows x 80B (bf16 [dim][node], chunk-XOR-swizzled)
//                  aliased after agg1: H1T [0,5120) 64x80B ; A2cat [5120,13824) 32x272B
//   [20480, 53760) Acat  32 rows x 1040B (bf16 [node][k=512])
//   [53760, 56320) M1    32 x 80B  (bf16 Ain[dst][src] = cnt*inv_in[dst])
//   [56320, 58880) M2    32 x 80B  (bf16 [src][dst] = cnt*inv_out[src])
//   [58880, 63104) C     32 x 33 int edge counts
//   [63104, 63232) inv_in  f32[32]
//   [63232, 63360) inv_out f32[32]
// ---------------------------------------------------------------------------
__global__ __launch_bounds__(256, 2) void graph_emb_kernel(
    const float* __restrict__ subj_embs, const float* __restrict__ obj_embs,
    const int* __restrict__ subj_src, const int* __restrict__ subj_dst,
    const int* __restrict__ obj_src, const int* __restrict__ obj_dst,
    const unsigned short* __restrict__ W1b, const unsigned short* __restrict__ W2b,
    const float* __restrict__ b1, const float* __restrict__ b2,
    float* __restrict__ g_out /* [2*BGR, 256] */)
{
  __shared__ __align__(16) unsigned char S[63360];
  int*   Cc      = (int*)(S + 58880);
  float* inv_in  = (float*)(S + 63104);
  float* inv_out = (float*)(S + 63232);

  const int t = threadIdx.x;
  const int w = t >> 6, l = t & 63;
  const int ln16 = l & 15, kg = l >> 4;
  const int bid = blockIdx.x;
  const int side = bid >> 12, g = bid & (BGR - 1);

  // ---- P0: zero counts, load edges, build counts, transpose embeddings ----
  for (int i = t; i < 1056; i += 256) Cc[i] = 0;
  int es = 0, ed = 0;
  if (t < 128) {
    es = (side ? obj_src : subj_src)[(g << 7) + t] & 31;
    ed = (side ? obj_dst : subj_dst)[(g << 7) + t] & 31;
  }
  __syncthreads();
  if (t < 128) atomicAdd(&Cc[ed * 33 + es], 1);
  {
    const float* eb = (side ? obj_embs : subj_embs) + ((size_t)(g << 5)) * DIM;
    const int v = t >> 3, s = t & 7;
    #pragma unroll
    for (int i = 0; i < 8; i++) {
      const int d0 = (s << 2) + (i << 5);
      float4 x = *(const float4*)(eb + v * DIM + d0);
      float xv[4] = {x.x, x.y, x.z, x.w};
      #pragma unroll
      for (int j = 0; j < 4; j++) {
        const int row = d0 + j;
        const int swz = ((row >> 2) ^ (row >> 4)) & 3;
        *(unsigned short*)(S + row * 80 + ((v * 2) ^ (swz << 4))) = f2b(xv[j]);
      }
    }
  }
  __syncthreads();

  // ---- P1: degrees -> inv, fill M1/M2 (bf16) ----
  if (t < 32) {
    int di = 0, dg = 0;
    #pragma unroll
    for (int s2 = 0; s2 < 32; s2++) { di += Cc[t * 33 + s2]; dg += Cc[s2 * 33 + t]; }
    inv_in[t]  = 1.0f / fmaxf((float)di, 1.0f);
    inv_out[t] = 1.0f / fmaxf((float)dg, 1.0f);
  }
  __syncthreads();
  {
    const int n = t >> 3, k0 = (t & 7) << 2;
    const float fi = inv_in[n], fo = inv_out[n];
    unsigned a0 = f2b((float)Cc[n * 33 + k0 + 0] * fi);
    unsigned a1 = f2b((float)Cc[n * 33 + k0 + 1] * fi);
    unsigned a2 = f2b((float)Cc[n * 33 + k0 + 2] * fi);
    unsigned a3 = f2b((float)Cc[n * 33 + k0 + 3] * fi);
    unsigned c0 = f2b((float)Cc[(k0 + 0) * 33 + n] * fo);
    unsigned c1 = f2b((float)Cc[(k0 + 1) * 33 + n] * fo);
    unsigned c2 = f2b((float)Cc[(k0 + 2) * 33 + n] * fo);
    unsigned c3 = f2b((float)Cc[(k0 + 3) * 33 + n] * fo);
    unsigned* pm1 = (unsigned*)(S + 53760 + n * 80 + k0 * 2);
    pm1[0] = a0 | (a1 << 16); pm1[1] = a2 | (a3 << 16);
    unsigned* pm2 = (unsigned*)(S + 56320 + n * 80 + k0 * 2);
    pm2[0] = c0 | (c1 << 16); pm2[1] = c2 | (c3 << 16);
  }
  __syncthreads();

  // ---- P2: agg1 via MFMA: D[dim][dst] = EbT @ M*^T ; write Acat[dst][dim] ----
  {
    bf16x8 Bf[2][2];
    #pragma unroll
    for (int nt = 0; nt < 2; nt++) {
      const int r = (nt << 4) + ln16;
      Bf[0][nt] = *(const bf16x8*)(S + 53760 + r * 80 + (kg << 4));
      Bf[1][nt] = *(const bf16x8*)(S + 56320 + r * 80 + (kg << 4));
    }
    #pragma unroll
    for (int mi = 0; mi < 4; mi++) {
      const int mt = (w << 2) + mi;
      const int m = (mt << 4) + ln16;                 // global dim row
      const int swz = ((m >> 2) ^ (m >> 4)) & 3;
      bf16x8 Af = *(const bf16x8*)(S + m * 80 + ((kg ^ swz) << 4));
      #pragma unroll
      for (int d = 0; d < 2; d++) {
        #pragma unroll
        for (int nt = 0; nt < 2; nt++) {
          f32x4 z = {0.f, 0.f, 0.f, 0.f};
          f32x4 r4 = __builtin_amdgcn_mfma_f32_16x16x32_bf16(Af, Bf[d][nt], z, 0, 0, 0);
          const int dst  = (nt << 4) + ln16;
          const int dim0 = (mt << 4) + (kg << 2) + (d << 8);
          u16x4 pk = { f2b(r4[0]), f2b(r4[1]), f2b(r4[2]), f2b(r4[3]) };
          *(u16x4*)(S + 20480 + dst * 1040 + dim0 * 2) = pk;
        }
      }
    }
  }
  __syncthreads();

  // ---- P3: gemm1: H1[node][j] = relu(Acat @ W1cat^T + b1); write H1T[j][node] ----
  {
    const int j = (w << 4) + ln16;
    bf16x8 Bf[16];
    #pragma unroll
    for (int ks = 0; ks < 16; ks++)
      Bf[ks] = *(const bf16x8*)(W1b + j * 512 + (ks << 5) + (kg << 3));
    f32x4 a0 = {0.f,0.f,0.f,0.f}, a1 = {0.f,0.f,0.f,0.f};
    #pragma unroll
    for (int ks = 0; ks < 16; ks++) {
      bf16x8 A0 = *(const bf16x8*)(S + 20480 + ln16 * 1040 + (ks << 6) + (kg << 4));
      bf16x8 A1 = *(const bf16x8*)(S + 20480 + (16 + ln16) * 1040 + (ks << 6) + (kg << 4));
      a0 = __builtin_amdgcn_mfma_f32_16x16x32_bf16(A0, Bf[ks], a0, 0, 0, 0);
      a1 = __builtin_amdgcn_mfma_f32_16x16x32_bf16(A1, Bf[ks], a1, 0, 0, 0);
    }
    const float bb = b1[j];
    u16x4 p0 = { f2b(fmaxf(a0[0]+bb,0.f)), f2b(fmaxf(a0[1]+bb,0.f)),
                 f2b(fmaxf(a0[2]+bb,0.f)), f2b(fmaxf(a0[3]+bb,0.f)) };
    u16x4 p1 = { f2b(fmaxf(a1[0]+bb,0.f)), f2b(fmaxf(a1[1]+bb,0.f)),
                 f2b(fmaxf(a1[2]+bb,0.f)), f2b(fmaxf(a1[3]+bb,0.f)) };
    *(u16x4*)(S + j * 80 + (kg << 3)) = p0;        // nodes 4kg..4kg+3
    *(u16x4*)(S + j * 80 + 32 + (kg << 3)) = p1;   // nodes 16+4kg..
  }
  __syncthreads();

  // ---- P4: agg2 via MFMA on H1T; write A2cat[dst][dim] ----
  {
    bf16x8 Bf[2][2];
    #pragma unroll
    for (int nt = 0; nt < 2; nt++) {
      const int r = (nt << 4) + ln16;
      Bf[0][nt] = *(const bf16x8*)(S + 53760 + r * 80 + (kg << 4));
      Bf[1][nt] = *(const bf16x8*)(S + 56320 + r * 80 + (kg << 4));
    }
    const int m = (w << 4) + ln16;                   // dim row of H1T (0..63)
    bf16x8 Af = *(const bf16x8*)(S + m * 80 + (kg << 4));
    #pragma unroll
    for (int d = 0; d < 2; d++) {
      #pragma unroll
      for (int nt = 0; nt < 2; nt++) {
        f32x4 z = {0.f,0.f,0.f,0.f};
        f32x4 r4 = __builtin_amdgcn_mfma_f32_16x16x32_bf16(Af, Bf[d][nt], z, 0, 0, 0);
        const int dst  = (nt << 4) + ln16;
        const int dim0 = (w << 4) + (kg << 2) + (d << 6);
        u16x4 pk = { f2b(r4[0]), f2b(r4[1]), f2b(r4[2]), f2b(r4[3]) };
        *(u16x4*)(S + 5120 + dst * 272 + dim0 * 2) = pk;
      }
    }
  }
  __syncthreads();

  // ---- P5: gemm2 + fused mean readout ----
  {
    bf16x8 Bf[4][4];
    #pragma unroll
    for (int nt = 0; nt < 4; nt++) {
      const int j = (w << 6) + (nt << 4) + ln16;
      #pragma unroll
      for (int ks = 0; ks < 4; ks++)
        Bf[nt][ks] = *(const bf16x8*)(W2b + j * 128 + (ks << 5) + (kg << 3));
    }
    f32x4 acc[2][4];
    #pragma unroll
    for (int mt = 0; mt < 2; mt++)
      #pragma unroll
      for (int nt = 0; nt < 4; nt++) { f32x4 z = {0.f,0.f,0.f,0.f}; acc[mt][nt] = z; }
    #pragma unroll
    for (int ks = 0; ks < 4; ks++) {
      bf16x8 A0 = *(const bf16x8*)(S + 5120 + ln16 * 272 + (ks << 6) + (kg << 4));
      bf16x8 A1 = *(const bf16x8*)(S + 5120 + (16 + ln16) * 272 + (ks << 6) + (kg << 4));
      #pragma unroll
      for (int nt = 0; nt < 4; nt++) {
        acc[0][nt] = __builtin_amdgcn_mfma_f32_16x16x32_bf16(A0, Bf[nt][ks], acc[0][nt], 0, 0, 0);
        acc[1][nt] = __builtin_amdgcn_mfma_f32_16x16x32_bf16(A1, Bf[nt][ks], acc[1][nt], 0, 0, 0);
      }
    }
    float* outp = g_out + ((size_t)(side * BGR + g)) * DIM;
    #pragma unroll
    for (int nt = 0; nt < 4; nt++) {
      const int j = (w << 6) + (nt << 4) + ln16;
      const float bb = b2[j];
      float sacc = 0.f;
      #pragma unroll
      for (int mt = 0; mt < 2; mt++)
        #pragma unroll
        for (int r = 0; r < 4; r++) sacc += fmaxf(acc[mt][nt][r] + bb, 0.f);
      sacc += __shfl_xor(sacc, 16);
      sacc += __shfl_xor(sacc, 32);
      if (kg == 0) outp[j] = sacc * 0.03125f;
    }
  }
}

// ---------------------------------------------------------------------------
// r_embs = relu(rel @ relW.T + relb). 16 rows per block. (fp32 VALU, small)
// ---------------------------------------------------------------------------
__global__ __launch_bounds__(256, 4) void rel_kernel(
    const float* __restrict__ rel, const float* __restrict__ relW,
    const float* __restrict__ relb, float* __restrict__ r_out)
{
  __shared__ float srel[16 * HS];
  const int t = threadIdx.x;
  const int b0 = blockIdx.x << 4;
  #pragma unroll
  for (int i = 0; i < 4; i++) {
    int f = (i << 8) + t;
    int r = f >> 6, k4 = f & 63;
    float4 x = *(const float4*)(rel + (size_t)(b0 + r) * DIM + (k4 << 2));
    float* d = &srel[r * HS + (k4 << 2)];
    d[0] = x.x; d[1] = x.y; d[2] = x.z; d[3] = x.w;
  }
  __syncthreads();
  const int r = t & 15, jg = t >> 4;
  const float* pa = &srel[r * HS];
  const float* w = relW + (size_t)(jg * 16) * DIM;
  float acc[16];
  #pragma unroll
  for (int jj = 0; jj < 16; jj++) acc[jj] = 0.f;
  for (int k0 = 0; k0 < DIM; k0 += 16) {
    float a[16];
    #pragma unroll
    for (int u = 0; u < 16; u++) a[u] = pa[k0 + u];
    #pragma unroll
    for (int jj = 0; jj < 16; jj++) {
      const float* wr = w + jj * DIM + k0;
      #pragma unroll
      for (int u = 0; u < 16; u += 4) {
        float4 wv = *(const float4*)(wr + u);
        acc[jj] += a[u]*wv.x + a[u+1]*wv.y + a[u+2]*wv.z + a[u+3]*wv.w;
      }
    }
  }
  float* outp = r_out + (size_t)(b0 + r) * DIM + jg * 16;
  #pragma unroll
  for (int jj = 0; jj < 16; jj++) outp[jj] = fmaxf(acc[jj] + relb[jg * 16 + jj], 0.f);
}

// ---------------------------------------------------------------------------
// Distances: pos = ||h+r-t||, neg = ||h[ch]+r-t[ct]||. One wave per triple.
// ---------------------------------------------------------------------------
__global__ __launch_bounds__(256) void dist_kernel(
    const float* __restrict__ hemb, const float* __restrict__ temb,
    const float* __restrict__ remb, const int* __restrict__ chx,
    const int* __restrict__ ctx, float* __restrict__ out)
{
  const int t = threadIdx.x;
  const int w = t >> 6, l = t & 63;
  const int b = (blockIdx.x << 2) + w;
  float4 h4 = *(const float4*)(hemb + (size_t)b * DIM + (l << 2));
  float4 r4 = *(const float4*)(remb + (size_t)b * DIM + (l << 2));
  float4 t4 = *(const float4*)(temb + (size_t)b * DIM + (l << 2));
  int hb = chx[b], tb = ctx[b];
  float4 hn = *(const float4*)(hemb + (size_t)hb * DIM + (l << 2));
  float4 tn = *(const float4*)(temb + (size_t)tb * DIM + (l << 2));
  float x0 = h4.x + r4.x - t4.x, x1 = h4.y + r4.y - t4.y;
  float x2 = h4.z + r4.z - t4.z, x3 = h4.w + r4.w - t4.w;
  float dp = x0*x0 + x1*x1 + x2*x2 + x3*x3;
  float y0 = hn.x + r4.x - tn.x, y1 = hn.y + r4.y - tn.y;
  float y2 = hn.z + r4.z - tn.z, y3 = hn.w + r4.w - tn.w;
  float dn = y0*y0 + y1*y1 + y2*y2 + y3*y3;
  #pragma unroll
  for (int off = 32; off >= 1; off >>= 1) {
    dp += __shfl_down(dp, off);
    dn += __shfl_down(dn, off);
  }
  if (l == 0) {
    out[b] = sqrtf(dp);
    out[BGR + b] = sqrtf(dn);
  }
}

extern "C" void kernel_launch(void* const* d_in, const int* in_sizes, int n_in,
                              void* d_out, int out_size, void* d_ws, size_t ws_size,
                              hipStream_t stream) {
  const float* subj_embs = (const float*)d_in[0];
  const float* obj_embs  = (const float*)d_in[1];
  const float* rel_tok   = (const float*)d_in[2];
  const int* subj_src = (const int*)d_in[3];
  const int* subj_dst = (const int*)d_in[4];
  const int* obj_src  = (const int*)d_in[5];
  const int* obj_dst  = (const int*)d_in[6];
  // d_in[7] = node_graph_ids (implicit by construction)
  const int* chx = (const int*)d_in[8];
  const int* ctx = (const int*)d_in[9];
  const float* WO1 = (const float*)d_in[10];
  const float* bO1 = (const float*)d_in[11];
  const float* WI1 = (const float*)d_in[12];
  const float* bI1 = (const float*)d_in[13];
  const float* WO2 = (const float*)d_in[14];
  const float* bO2 = (const float*)d_in[15];
  const float* WI2 = (const float*)d_in[16];
  const float* bI2 = (const float*)d_in[17];
  const float* relW = (const float*)d_in[18];
  const float* relb = (const float*)d_in[19];

  float* g_embs = (float*)d_ws;                           // [8192,256] f32 = 8 MB
  float* r_embs = g_embs + (size_t)2 * BGR * DIM;         // [4096,256] f32 = 4 MB
  unsigned short* W1b = (unsigned short*)((char*)d_ws + 12582912);  // 64 KB
  unsigned short* W2b = W1b + 32768;                                // 64 KB
  float* b1 = (float*)((char*)d_ws + 12713984);                     // 256 B
  float* b2 = b1 + 64;                                              // 1 KB
  float* out = (float*)d_out;                             // [8192]: pos | neg

  wcvt_kernel<<<128, 256, 0, stream>>>(WO1, WI1, WO2, WI2, bO1, bI1, bO2, bI2,
                                       W1b, W2b, b1, b2);
  graph_emb_kernel<<<2 * BGR, 256, 0, stream>>>(
      subj_embs, obj_embs, subj_src, subj_dst, obj_src, obj_dst,
      W1b, W2b, b1, b2, g_embs);
  rel_kernel<<<BGR / 16, 256, 0, stream>>>(rel_tok, relW, relb, r_embs);
  dist_kernel<<<BGR / 4, 256, 0, stream>>>(
      g_embs, g_embs + (size_t)BGR * DIM, r_embs, chx, ctx, out);
}

// Round 3
// 232.958 us; speedup vs baseline: 9.0857x; 1.0782x over previous
//
#include <hip/hip_runtime.h>
#include <hip/hip_bf16.h>

#define BGR 4096      // graphs per side
#define DIM 256
#define HS  257       // LDS row stride for rel_kernel (fp32)

typedef __bf16 bf16x8 __attribute__((ext_vector_type(8)));
typedef float  f32x4  __attribute__((ext_vector_type(4)));
typedef unsigned short u16x4 __attribute__((ext_vector_type(4)));
typedef unsigned short u16x8 __attribute__((ext_vector_type(8)));

__device__ __forceinline__ unsigned short f2b(float f) {
  unsigned u = __builtin_bit_cast(unsigned, f);
  u = (u + 0x7FFFu + ((u >> 16) & 1u)) >> 16;   // RNE
  return (unsigned short)u;
}

// ---------------------------------------------------------------------------
// Weight prep: W1b = [WO1;WI1] bf16 [128 rows][256 k]  (rows 0-63 WO1, 64-127 WI1)
//              W2b = [WO2|WI2] bf16 [256 rows][128 k]  (k 0-63 WO2, 64-127 WI2)
//              b1 = bO1+bI1 (f32[64]), b2 = bO2+bI2 (f32[256]).
// ---------------------------------------------------------------------------
__global__ void wcvt_kernel(
    const float* __restrict__ WO1, const float* __restrict__ WI1,
    const float* __restrict__ WO2, const float* __restrict__ WI2,
    const float* __restrict__ bO1, const float* __restrict__ bI1,
    const float* __restrict__ bO2, const float* __restrict__ bI2,
    unsigned short* __restrict__ W1b, unsigned short* __restrict__ W2b,
    float* __restrict__ b1, float* __restrict__ b2)
{
  const int i = blockIdx.x * 256 + threadIdx.x;   // 0..32767
  { int j = i >> 8, k = i & 255;
    float v = (j < 64) ? WO1[j * 256 + k] : WI1[(j - 64) * 256 + k];
    W1b[i] = f2b(v); }
  { int j = i >> 7, k = i & 127;
    float v = (k < 64) ? WO2[j * 64 + k] : WI2[j * 64 + (k - 64)];
    W2b[i] = f2b(v); }
  if (i < 64)  b1[i] = bO1[i] + bI1[i];
  if (i < 256) b2[i] = bO2[i] + bI2[i];
}

// ---------------------------------------------------------------------------
// Fused per-graph: Y = E@W1catT (gemm0) -> H1T = relu(agg1) -> A2cat = agg2
// -> H2 = relu(A2cat@W2catT + b2) -> mean readout. One block per (side,graph).
// 256 threads = 4 waves. All MFMA; zero scalar LDS writes.
//
// LDS (36608 B):
//   [0,     16896) Ecvt  32 rows x 528B  (bf16 E tile)   | alias: H1T 64 x 80B
//   [16896, 27136) YT    128 rows x 80B  ([j][node])     | alias: A2cat 32 x 272B
//   [27136, 29696) M1    32 x 80B  (Ain[dst][src] bf16)
//   [29696, 32256) M2    32 x 80B  (Aout[src][dst]... stored [n][k] natural)
//   [32256, 36352) Cc    32x32 int edge counts
//   [36352, 36608) inv_in f32[32], inv_out f32[32]
// ---------------------------------------------------------------------------
#define OFF_E   0
#define OFF_H1T 0
#define OFF_YT  16896
#define OFF_A2  16896
#define OFF_M1  27136
#define OFF_M2  29696
#define OFF_CC  32256
#define OFF_INV 36352

__global__ __launch_bounds__(256, 4) void graph_emb_kernel(
    const float* __restrict__ subj_embs, const float* __restrict__ obj_embs,
    const int* __restrict__ subj_src, const int* __restrict__ subj_dst,
    const int* __restrict__ obj_src, const int* __restrict__ obj_dst,
    const unsigned short* __restrict__ W1b, const unsigned short* __restrict__ W2b,
    const float* __restrict__ b1, const float* __restrict__ b2,
    float* __restrict__ g_out /* [2*BGR, 256] */)
{
  __shared__ __align__(16) unsigned char S[36608];
  int*   Cc      = (int*)(S + OFF_CC);
  float* inv_in  = (float*)(S + OFF_INV);
  float* inv_out = (float*)(S + OFF_INV + 128);

  const int t = threadIdx.x;
  const int l = t & 63, w = t >> 6;
  const int ln16 = l & 15, kg = l >> 4;
  const int bid = blockIdx.x;
  const int side = bid >> 12, g = bid & (BGR - 1);

  // ---- P0: zero counts; load edges; load E tile (32x256 f32) ----
  #pragma unroll
  for (int i = 0; i < 4; i++) ((int*)(S + OFF_CC))[t + (i << 8)] = 0;
  int es = 0, ed = 0;
  if (t < 128) {
    es = (side ? obj_src : subj_src)[(g << 7) + t] & 31;
    ed = (side ? obj_dst : subj_dst)[(g << 7) + t] & 31;
  }
  const float* eb = (side ? obj_embs : subj_embs)
                    + ((size_t)(g << 5) + (t >> 3)) * DIM + ((t & 7) << 5);
  const float4* ef = (const float4*)eb;
  float4 q0 = ef[0], q1 = ef[1], q2 = ef[2], q3 = ef[3];
  float4 q4 = ef[4], q5 = ef[5], q6 = ef[6], q7 = ef[7];
  __syncthreads();                        // Cc zeroed
  if (t < 128) atomicAdd(&Cc[(ed << 5) + es], 1);
  {
    unsigned short* erow = (unsigned short*)(S + OFF_E + (t >> 3) * 528) + ((t & 7) << 5);
    float4 qa[8] = {q0, q1, q2, q3, q4, q5, q6, q7};
    #pragma unroll
    for (int i = 0; i < 4; i++) {
      float4 a = qa[2 * i], b = qa[2 * i + 1];
      u16x8 pk = { f2b(a.x), f2b(a.y), f2b(a.z), f2b(a.w),
                   f2b(b.x), f2b(b.y), f2b(b.z), f2b(b.w) };
      *(u16x8*)(erow + (i << 3)) = pk;
    }
  }
  __syncthreads();                        // counts + Ecvt complete

  // ---- P1: degree inverses ----
  if (t < 32) {
    int di = 0, dg = 0;
    #pragma unroll
    for (int s2 = 0; s2 < 32; s2++) { di += Cc[(t << 5) + s2]; dg += Cc[(s2 << 5) + t]; }
    inv_in[t]  = 1.0f / fmaxf((float)di, 1.0f);
    inv_out[t] = 1.0f / fmaxf((float)dg, 1.0f);
  }
  __syncthreads();

  // ---- P2: build M1[dst][src], M2[src][dst] (bf16, stride 80B) ----
  {
    const int n = t >> 3, k0 = (t & 7) << 2;
    const float fi = inv_in[n], fo = inv_out[n];
    u16x4 m1 = { f2b((float)Cc[(n << 5) + k0 + 0] * fi),
                 f2b((float)Cc[(n << 5) + k0 + 1] * fi),
                 f2b((float)Cc[(n << 5) + k0 + 2] * fi),
                 f2b((float)Cc[(n << 5) + k0 + 3] * fi) };
    u16x4 m2 = { f2b((float)Cc[((k0 + 0) << 5) + n] * fo),
                 f2b((float)Cc[((k0 + 1) << 5) + n] * fo),
                 f2b((float)Cc[((k0 + 2) << 5) + n] * fo),
                 f2b((float)Cc[((k0 + 3) << 5) + n] * fo) };
    *(u16x4*)(S + OFF_M1 + n * 80 + (k0 << 1)) = m1;
    *(u16x4*)(S + OFF_M2 + n * 80 + (k0 << 1)) = m2;
  }

  // ---- gemm0: Y[node][j128] = E @ W1catT; vector-write YT[j][node] ----
  {
    f32x4 a00 = {0,0,0,0}, a01 = {0,0,0,0}, a10 = {0,0,0,0}, a11 = {0,0,0,0};
    const unsigned short* wb = W1b + (((w << 5) + ln16) << 8) + (kg << 3);
    const unsigned char* ea = S + OFF_E + ln16 * 528 + (kg << 4);
    #pragma unroll
    for (int ks = 0; ks < 8; ks++) {
      bf16x8 A0 = *(const bf16x8*)(ea + (ks << 6));
      bf16x8 A1 = *(const bf16x8*)(ea + 16 * 528 + (ks << 6));
      bf16x8 B0 = *(const bf16x8*)(wb + (ks << 5));
      bf16x8 B1 = *(const bf16x8*)(wb + 4096 + (ks << 5));
      a00 = __builtin_amdgcn_mfma_f32_16x16x32_bf16(A0, B0, a00, 0, 0, 0);
      a01 = __builtin_amdgcn_mfma_f32_16x16x32_bf16(A0, B1, a01, 0, 0, 0);
      a10 = __builtin_amdgcn_mfma_f32_16x16x32_bf16(A1, B0, a10, 0, 0, 0);
      a11 = __builtin_amdgcn_mfma_f32_16x16x32_bf16(A1, B1, a11, 0, 0, 0);
    }
    // C[m=node][n=j] -> YT[j][node], j = w*32 + nt*16 + ln16, node = mt*16+kg*4+r
    f32x4 av[4] = {a00, a01, a10, a11};
    #pragma unroll
    for (int mt = 0; mt < 2; mt++)
      #pragma unroll
      for (int nt = 0; nt < 2; nt++) {
        f32x4 c = av[mt * 2 + nt];
        u16x4 pk = { f2b(c[0]), f2b(c[1]), f2b(c[2]), f2b(c[3]) };
        *(u16x4*)(S + OFF_YT + ((w << 5) + (nt << 4) + ln16) * 80 + (mt << 5) + (kg << 3)) = pk;
      }
  }
  __syncthreads();   // YT + M1/M2 ready

  // ---- step1: H1T[j64][node] = relu(Ain@Yo + Aout@Yi + b1) (transposed write) ----
  {
    bf16x8 Byo = *(const bf16x8*)(S + OFF_YT + ((w << 4) + ln16) * 80 + (kg << 4));
    bf16x8 Byi = *(const bf16x8*)(S + OFF_YT + (64 + (w << 4) + ln16) * 80 + (kg << 4));
    const float b1j = b1[(w << 4) + ln16];
    #pragma unroll
    for (int mt = 0; mt < 2; mt++) {
      bf16x8 Ao = *(const bf16x8*)(S + OFF_M1 + ((mt << 4) + ln16) * 80 + (kg << 4));
      bf16x8 Ai = *(const bf16x8*)(S + OFF_M2 + ((mt << 4) + ln16) * 80 + (kg << 4));
      f32x4 c = {0,0,0,0};
      c = __builtin_amdgcn_mfma_f32_16x16x32_bf16(Ao, Byo, c, 0, 0, 0);
      c = __builtin_amdgcn_mfma_f32_16x16x32_bf16(Ai, Byi, c, 0, 0, 0);
      u16x4 pk = { f2b(fmaxf(c[0] + b1j, 0.f)), f2b(fmaxf(c[1] + b1j, 0.f)),
                   f2b(fmaxf(c[2] + b1j, 0.f)), f2b(fmaxf(c[3] + b1j, 0.f)) };
      *(u16x4*)(S + OFF_H1T + ((w << 4) + ln16) * 80 + (mt << 5) + (kg << 3)) = pk;
    }
  }
  __syncthreads();   // H1T ready (YT now dead)

  // ---- step2: A2cat[dst][128] = [Ain@H1 | Aout@H1] via A2T = H1T @ M^T ----
  {
    bf16x8 Ah = *(const bf16x8*)(S + OFF_H1T + ((w << 4) + ln16) * 80 + (kg << 4));
    #pragma unroll
    for (int half = 0; half < 2; half++) {
      #pragma unroll
      for (int nt = 0; nt < 2; nt++) {
        bf16x8 B = *(const bf16x8*)(S + (half ? OFF_M2 : OFF_M1)
                                    + ((nt << 4) + ln16) * 80 + (kg << 4));
        f32x4 c = {0,0,0,0};
        c = __builtin_amdgcn_mfma_f32_16x16x32_bf16(Ah, B, c, 0, 0, 0);
        // C[m=j = w*16+kg*4+r][n=dst = nt*16+ln16] -> A2cat[dst][half*64 + j]
        u16x4 pk = { f2b(c[0]), f2b(c[1]), f2b(c[2]), f2b(c[3]) };
        *(u16x4*)(S + OFF_A2 + ((nt << 4) + ln16) * 272
                  + (half << 7) + (w << 5) + (kg << 3)) = pk;
      }
    }
  }
  __syncthreads();   // A2cat ready (H1T dead)

  // ---- step3: H2T[j256][node] = W2b @ A2catT, fused relu+bias+mean readout ----
  {
    f32x4 acc[4][2];
    #pragma unroll
    for (int mt = 0; mt < 4; mt++) { f32x4 z = {0,0,0,0}; acc[mt][0] = z; acc[mt][1] = z; }
    const unsigned short* wa = W2b + (((w << 6) + ln16) << 7) + (kg << 3);
    #pragma unroll
    for (int ks = 0; ks < 4; ks++) {
      bf16x8 B0 = *(const bf16x8*)(S + OFF_A2 + ln16 * 272 + (ks << 6) + (kg << 4));
      bf16x8 B1 = *(const bf16x8*)(S + OFF_A2 + (16 + ln16) * 272 + (ks << 6) + (kg << 4));
      #pragma unroll
      for (int mt = 0; mt < 4; mt++) {
        bf16x8 A = *(const bf16x8*)(wa + (mt << 11) + (ks << 5));
        acc[mt][0] = __builtin_amdgcn_mfma_f32_16x16x32_bf16(A, B0, acc[mt][0], 0, 0, 0);
        acc[mt][1] = __builtin_amdgcn_mfma_f32_16x16x32_bf16(A, B1, acc[mt][1], 0, 0, 0);
      }
    }
    float* outp = g_out + ((size_t)(side * BGR + g)) * DIM;
    #pragma unroll
    for (int mt = 0; mt < 4; mt++) {
      const int jb = (w << 6) + (mt << 4) + (kg << 2);
      float s0 = fmaxf(acc[mt][0][0] + b2[jb + 0], 0.f) + fmaxf(acc[mt][1][0] + b2[jb + 0], 0.f);
      float s1 = fmaxf(acc[mt][0][1] + b2[jb + 1], 0.f) + fmaxf(acc[mt][1][1] + b2[jb + 1], 0.f);
      float s2 = fmaxf(acc[mt][0][2] + b2[jb + 2], 0.f) + fmaxf(acc[mt][1][2] + b2[jb + 2], 0.f);
      float s3 = fmaxf(acc[mt][0][3] + b2[jb + 3], 0.f) + fmaxf(acc[mt][1][3] + b2[jb + 3], 0.f);
      #pragma unroll
      for (int d = 1; d < 16; d <<= 1) {
        s0 += __shfl_xor(s0, d); s1 += __shfl_xor(s1, d);
        s2 += __shfl_xor(s2, d); s3 += __shfl_xor(s3, d);
      }
      if (ln16 == 0) {
        outp[jb + 0] = s0 * 0.03125f;
        outp[jb + 1] = s1 * 0.03125f;
        outp[jb + 2] = s2 * 0.03125f;
        outp[jb + 3] = s3 * 0.03125f;
      }
    }
  }
}

// ---------------------------------------------------------------------------
// r_embs = relu(rel @ relW.T + relb). 16 rows per block. (fp32 VALU)
// ---------------------------------------------------------------------------
__global__ __launch_bounds__(256, 4) void rel_kernel(
    const float* __restrict__ rel, const float* __restrict__ relW,
    const float* __restrict__ relb, float* __restrict__ r_out)
{
  __shared__ float srel[16 * HS];
  const int t = threadIdx.x;
  const int b0 = blockIdx.x << 4;
  #pragma unroll
  for (int i = 0; i < 4; i++) {
    int f = (i << 8) + t;
    int r = f >> 6, k4 = f & 63;
    float4 x = *(const float4*)(rel + (size_t)(b0 + r) * DIM + (k4 << 2));
    float* d = &srel[r * HS + (k4 << 2)];
    d[0] = x.x; d[1] = x.y; d[2] = x.z; d[3] = x.w;
  }
  __syncthreads();
  const int r = t & 15, jg = t >> 4;
  const float* pa = &srel[r * HS];
  const float* w = relW + (size_t)(jg * 16) * DIM;
  float acc[16];
  #pragma unroll
  for (int jj = 0; jj < 16; jj++) acc[jj] = 0.f;
  for (int k0 = 0; k0 < DIM; k0 += 16) {
    float a[16];
    #pragma unroll
    for (int u = 0; u < 16; u++) a[u] = pa[k0 + u];
    #pragma unroll
    for (int jj = 0; jj < 16; jj++) {
      const float* wr = w + jj * DIM + k0;
      #pragma unroll
      for (int u = 0; u < 16; u += 4) {
        float4 wv = *(const float4*)(wr + u);
        acc[jj] += a[u]*wv.x + a[u+1]*wv.y + a[u+2]*wv.z + a[u+3]*wv.w;
      }
    }
  }
  float* outp = r_out + (size_t)(b0 + r) * DIM + jg * 16;
  #pragma unroll
  for (int jj = 0; jj < 16; jj++) outp[jj] = fmaxf(acc[jj] + relb[jg * 16 + jj], 0.f);
}

// ---------------------------------------------------------------------------
// Distances: pos = ||h+r-t||, neg = ||h[ch]+r-t[ct]||. One wave per triple.
// ---------------------------------------------------------------------------
__global__ __launch_bounds__(256) void dist_kernel(
    const float* __restrict__ hemb, const float* __restrict__ temb,
    const float* __restrict__ remb, const int* __restrict__ chx,
    const int* __restrict__ ctx, float* __restrict__ out)
{
  const int t = threadIdx.x;
  const int w = t >> 6, l = t & 63;
  const int b = (blockIdx.x << 2) + w;
  float4 h4 = *(const float4*)(hemb + (size_t)b * DIM + (l << 2));
  float4 r4 = *(const float4*)(remb + (size_t)b * DIM + (l << 2));
  float4 t4 = *(const float4*)(temb + (size_t)b * DIM + (l << 2));
  int hb = chx[b], tb = ctx[b];
  float4 hn = *(const float4*)(hemb + (size_t)hb * DIM + (l << 2));
  float4 tn = *(const float4*)(temb + (size_t)tb * DIM + (l << 2));
  float x0 = h4.x + r4.x - t4.x, x1 = h4.y + r4.y - t4.y;
  float x2 = h4.z + r4.z - t4.z, x3 = h4.w + r4.w - t4.w;
  float dp = x0*x0 + x1*x1 + x2*x2 + x3*x3;
  float y0 = hn.x + r4.x - tn.x, y1 = hn.y + r4.y - tn.y;
  float y2 = hn.z + r4.z - tn.z, y3 = hn.w + r4.w - tn.w;
  float dn = y0*y0 + y1*y1 + y2*y2 + y3*y3;
  #pragma unroll
  for (int off = 32; off >= 1; off >>= 1) {
    dp += __shfl_down(dp, off);
    dn += __shfl_down(dn, off);
  }
  if (l == 0) {
    out[b] = sqrtf(dp);
    out[BGR + b] = sqrtf(dn);
  }
}

extern "C" void kernel_launch(void* const* d_in, const int* in_sizes, int n_in,
                              void* d_out, int out_size, void* d_ws, size_t ws_size,
                              hipStream_t stream) {
  const float* subj_embs = (const float*)d_in[0];
  const float* obj_embs  = (const float*)d_in[1];
  const float* rel_tok   = (const float*)d_in[2];
  const int* subj_src = (const int*)d_in[3];
  const int* subj_dst = (const int*)d_in[4];
  const int* obj_src  = (const int*)d_in[5];
  const int* obj_dst  = (const int*)d_in[6];
  // d_in[7] = node_graph_ids (implicit by construction)
  const int* chx = (const int*)d_in[8];
  const int* ctx = (const int*)d_in[9];
  const float* WO1 = (const float*)d_in[10];
  const float* bO1 = (const float*)d_in[11];
  const float* WI1 = (const float*)d_in[12];
  const float* bI1 = (const float*)d_in[13];
  const float* WO2 = (const float*)d_in[14];
  const float* bO2 = (const float*)d_in[15];
  const float* WI2 = (const float*)d_in[16];
  const float* bI2 = (const float*)d_in[17];
  const float* relW = (const float*)d_in[18];
  const float* relb = (const float*)d_in[19];

  float* g_embs = (float*)d_ws;                           // [8192,256] f32 = 8 MB
  float* r_embs = g_embs + (size_t)2 * BGR * DIM;         // [4096,256] f32 = 4 MB
  unsigned short* W1b = (unsigned short*)((char*)d_ws + 12582912);  // 64 KB
  unsigned short* W2b = W1b + 32768;                                // 64 KB
  float* b1 = (float*)((char*)d_ws + 12713984);                     // 256 B
  float* b2 = b1 + 64;                                              // 1 KB
  float* out = (float*)d_out;                             // [8192]: pos | neg

  wcvt_kernel<<<128, 256, 0, stream>>>(WO1, WI1, WO2, WI2, bO1, bI1, bO2, bI2,
                                       W1b, W2b, b1, b2);
  graph_emb_kernel<<<2 * BGR, 256, 0, stream>>>(
      subj_embs, obj_embs, subj_src, subj_dst, obj_src, obj_dst,
      W1b, W2b, b1, b2, g_embs);
  rel_kernel<<<BGR / 16, 256, 0, stream>>>(rel_tok, relW, relb, r_embs);
  dist_kernel<<<BGR / 4, 256, 0, stream>>>(
      g_embs, g_embs + (size_t)BGR * DIM, r_embs, chx, ctx, out);
}